// Round 9
// baseline (706.079 us; speedup 1.0000x reference)
//
#include <hip/hip_runtime.h>
#include <math.h>

#define NG 32
#define T_N 40704           // density tile: 40704 floats = 159.0 KB LDS
#define T_C 20352           // force tile: 20352 packed doubles = 159.0 KB LDS

// f64 packing constants: p = rint(32 fx)*2^33 + rint(32 fy)*2^17 + fz
#define PK_Q   32.0f
#define PK_K1  8589934592.0   // 2^33
#define PK_K2  131072.0       // 2^17

__device__ __forceinline__ float softplus_f(float x) {
    return (x > 0.f) ? (x + log1pf(expf(-x))) : log1pf(expf(x));
}

__device__ __forceinline__ void lds_fadd64(double* p, double v) {
#if defined(__HIP_PLATFORM_AMD__) || defined(__AMDGCN__)
    unsafeAtomicAdd(p, v);      // ds_add_f64 on gfx90a+
#else
    atomicAdd(p, v);
#endif
}

// gid -> (tile t, chunk c) with all tiles of a chunk on one XCD (gid%8 == c%8),
// assuming round-robin workgroup->XCD dispatch. Requires NC % 8 == 0; else identity.
__device__ __forceinline__ void map_tc(int gid, int NT, int NC, int* t, int* c) {
    if ((NC & 7) == 0) {
        int x = gid & 7, s = gid >> 3;
        *t = s % NT;
        *c = (s / NT) * 8 + x;
    } else {
        *t = gid / NC;
        *c = gid - (*t) * NC;
    }
}

// K1: pure streaming map: r -> dens
__global__ __launch_bounds__(256) void k1_dens(
        const float* __restrict__ r,
        const float* __restrict__ p_da, const float* __restrict__ p_dl,
        float* __restrict__ dens_arr, int E)
{
    const float Ad = softplus_f(*p_da), Ld = softplus_f(*p_dl);
    const float4* r4 = (const float4*)r;
    float4* dens4 = (float4*)dens_arr;
    const int NQ = E >> 2;
    const int stride = gridDim.x * blockDim.x;
    for (int q = blockIdx.x*blockDim.x + threadIdx.x; q < NQ; q += stride) {
        float4 a = r4[3*q], b = r4[3*q+1], c = r4[3*q+2];
        float bl0 = sqrtf(a.x*a.x + a.y*a.y + a.z*a.z);
        float bl1 = sqrtf(a.w*a.w + b.x*b.x + b.y*b.y);
        float bl2 = sqrtf(b.z*b.z + b.w*b.w + c.x*c.x);
        float bl3 = sqrtf(c.y*c.y + c.z*c.z + c.w*c.w);
        float4 dv = { Ad*expf(-Ld*bl0), Ad*expf(-Ld*bl1),
                      Ad*expf(-Ld*bl2), Ad*expf(-Ld*bl3) };
        dens4[q] = dv;
    }
    for (int e = (NQ<<2) + blockIdx.x*blockDim.x + threadIdx.x; e < E; e += stride) {
        float x = r[3*e], y = r[3*e+1], z = r[3*e+2];
        float bl = sqrtf(x*x + y*y + z*z);
        dens_arr[e] = Ad*expf(-Ld*bl);
    }
}

// K2: density scatter into 159KB LDS node tile (proven shape)
__global__ __launch_bounds__(512) void k2_dens_tiles(
        const float* __restrict__ dens_arr, const int* __restrict__ dst,
        float* __restrict__ scratch, int E, int NT, int NC)
{
    __shared__ float sd[T_N];
    int t, k;
    map_tc(blockIdx.x, NT, NC, &t, &k);
    const int base = t * T_N;
    for (int i = threadIdx.x; i < T_N; i += blockDim.x) sd[i] = 0.f;
    __syncthreads();
    const int NQ = E >> 2;
    const int cq = (NQ + NC - 1) / NC;
    const int q0 = k*cq;
    const int q1 = (q0 + cq < NQ) ? (q0 + cq) : NQ;
    const float4* dens4 = (const float4*)dens_arr;
    const int4*   d4 = (const int4*)dst;
    for (int q = q0 + (int)threadIdx.x; q < q1; q += (int)blockDim.x) {
        float4 dv = dens4[q]; int4 dd = d4[q];
        unsigned l;
        l = (unsigned)(dd.x - base); if (l < T_N) atomicAdd(&sd[l], dv.x);
        l = (unsigned)(dd.y - base); if (l < T_N) atomicAdd(&sd[l], dv.y);
        l = (unsigned)(dd.z - base); if (l < T_N) atomicAdd(&sd[l], dv.z);
        l = (unsigned)(dd.w - base); if (l < T_N) atomicAdd(&sd[l], dv.w);
    }
    if (k == NC-1) {
        for (int e = (NQ<<2) + (int)threadIdx.x; e < E; e += (int)blockDim.x) {
            unsigned l = (unsigned)(dst[e] - base);
            if (l < T_N) atomicAdd(&sd[l], dens_arr[e]);
        }
    }
    __syncthreads();
    size_t sb = (size_t)(t * NC + k) * T_N;
    for (int i = threadIdx.x; i < T_N; i += blockDim.x) scratch[sb + i] = sd[i];
}

// K3: reduce density chunks; embedding energy -> bins; g = dE/d(local_density)
__global__ __launch_bounds__(256) void k3_node(
        const float* __restrict__ scratch, const int* __restrict__ n2g,
        const float* __restrict__ p_ea,
        float* __restrict__ g_out, float* __restrict__ e_graph, int N, int NC)
{
    __shared__ float sbin[NG];
    if (threadIdx.x < NG) sbin[threadIdx.x] = 0.f;
    __syncthreads();
    const float Ae = softplus_f(*p_ea);
    int n = blockIdx.x*blockDim.x + threadIdx.x;
    if (n < N) {
        int t = n / T_N; int off = n - t*T_N;
        const float* bp = scratch + ((size_t)t*NC)*T_N + off;
        float l = 0.f;
        for (int k = 0; k < NC; ++k) l += bp[(size_t)k*T_N];
        float s = sqrtf(fmaxf(l, 1e-12f));
        atomicAdd(&sbin[n2g[n]], -Ae*s);
        g_out[n] = (l >= 1e-12f) ? (-0.5f*Ae/s) : 0.f;
    }
    __syncthreads();
    if (threadIdx.x < NG) atomicAdd(&e_graph[threadIdx.x], sbin[threadIdx.x]);
}

// pack 3 force comps into one f64: rint(32x)*2^33 + rint(32y)*2^17 + z
__device__ __forceinline__ double pk3(float fx, float fy, float fz) {
    double hx = (double)rintf(fx * PK_Q);
    double hy = (double)rintf(fy * PK_Q);
    return hx * PK_K1 + hy * PK_K2 + (double)fz;
}

// K4: per-edge dE/dr packed to f64 pd[e]; repulsive -> 8x-replicated graph bins
// (R7 gather structure: n2g/g via L2-pipelined global gathers — NO dependent-chain search)
__global__ __launch_bounds__(256) void k4_pd8(
        const float* __restrict__ r, const int* __restrict__ dst,
        const int* __restrict__ n2g, const float* __restrict__ g,
        const float* __restrict__ p_da, const float* __restrict__ p_dl,
        const float* __restrict__ p_ra, const float* __restrict__ p_rl,
        double* __restrict__ pd, float* __restrict__ e_graph, int E)
{
    __shared__ float sbin[NG*8];
    sbin[threadIdx.x] = 0.f;          // blockDim == 256 == NG*8
    __syncthreads();
    const float Ad = softplus_f(*p_da), Ld = softplus_f(*p_dl);
    const float Ar = softplus_f(*p_ra), Lr = softplus_f(*p_rl);
    const float4* r4 = (const float4*)r;
    const int4*   d4 = (const int4*)dst;
    const int NQ = E >> 2;
    const int stride = gridDim.x * blockDim.x;
    const int rep_slot = ((int)threadIdx.x & 7) << 5;
    for (int q = blockIdx.x*blockDim.x + threadIdx.x; q < NQ; q += stride) {
        float4 a = r4[3*q], b = r4[3*q+1], c = r4[3*q+2];
        int4 dd = d4[q];
        float g0 = g[dd.x], g1 = g[dd.y], g2 = g[dd.z], g3 = g[dd.w];
        int b0 = n2g[dd.x], b1 = n2g[dd.y], b2 = n2g[dd.z], b3 = n2g[dd.w];
        float bl0 = sqrtf(a.x*a.x + a.y*a.y + a.z*a.z);
        float bl1 = sqrtf(a.w*a.w + b.x*b.x + b.y*b.y);
        float bl2 = sqrtf(b.z*b.z + b.w*b.w + c.x*c.x);
        float bl3 = sqrtf(c.y*c.y + c.z*c.z + c.w*c.w);
        float rep0 = Ar*expf(-Lr*bl0), rep1 = Ar*expf(-Lr*bl1);
        float rep2 = Ar*expf(-Lr*bl2), rep3 = Ar*expf(-Lr*bl3);
        float de0 = g0*(-Ld*Ad*expf(-Ld*bl0)) - Lr*rep0;
        float de1 = g1*(-Ld*Ad*expf(-Ld*bl1)) - Lr*rep1;
        float de2 = g2*(-Ld*Ad*expf(-Ld*bl2)) - Lr*rep2;
        float de3 = g3*(-Ld*Ad*expf(-Ld*bl3)) - Lr*rep3;
        float s0 = (bl0 > 0.f) ? de0/bl0 : 0.f;
        float s1 = (bl1 > 0.f) ? de1/bl1 : 0.f;
        float s2 = (bl2 > 0.f) ? de2/bl2 : 0.f;
        float s3 = (bl3 > 0.f) ? de3/bl3 : 0.f;
        pd[4*q+0] = pk3(s0*a.x, s0*a.y, s0*a.z);
        pd[4*q+1] = pk3(s1*a.w, s1*b.x, s1*b.y);
        pd[4*q+2] = pk3(s2*b.z, s2*b.w, s2*c.x);
        pd[4*q+3] = pk3(s3*c.y, s3*c.z, s3*c.w);
        atomicAdd(&sbin[b0 + rep_slot], rep0);
        atomicAdd(&sbin[b1 + rep_slot], rep1);
        atomicAdd(&sbin[b2 + rep_slot], rep2);
        atomicAdd(&sbin[b3 + rep_slot], rep3);
    }
    for (int e = (NQ<<2) + blockIdx.x*blockDim.x + threadIdx.x; e < E; e += stride) {
        float x = r[3*e], y = r[3*e+1], z = r[3*e+2];
        float bl = sqrtf(x*x + y*y + z*z);
        int de = dst[e];
        float rep = Ar*expf(-Lr*bl);
        float dEdb = g[de]*(-Ld*Ad*expf(-Ld*bl)) - Lr*rep;
        float s = (bl > 0.f) ? dEdb/bl : 0.f;
        pd[e] = pk3(s*x, s*y, s*z);
        atomicAdd(&sbin[n2g[de] + rep_slot], rep);
    }
    __syncthreads();
    atomicAdd(&e_graph[threadIdx.x & (NG-1)], sbin[threadIdx.x]);
}

__device__ __forceinline__ void fscat64(double* sf, int base, int d, int s, double p) {
    unsigned ld = (unsigned)(d - base);
    if (ld < T_C) lds_fadd64(&sf[ld], -p);
    unsigned ls = (unsigned)(s - base);
    if (ls < T_C) lds_fadd64(&sf[ls],  p);
}

// K5: force scatter; ONE packed f64 LDS atomic per taken endpoint (pd precomputed)
__global__ __launch_bounds__(512) void k5_pk64(
        const double* __restrict__ pd, const int* __restrict__ src,
        const int* __restrict__ dst,
        double* __restrict__ scratch, int E, int NT, int NC)
{
    __shared__ double sf[T_C];
    int t, c;
    map_tc(blockIdx.x, NT, NC, &t, &c);
    const int base = t * T_C;
    for (int i = threadIdx.x; i < T_C; i += blockDim.x) sf[i] = 0.0;
    __syncthreads();
    const int NQ = E >> 2;
    const int cq = (NQ + NC - 1) / NC;
    const int q0 = c*cq;
    const int q1 = (q0 + cq < NQ) ? (q0 + cq) : NQ;
    const double2* pd2 = (const double2*)pd;
    const int4* d4 = (const int4*)dst;
    const int4* s4 = (const int4*)src;
    for (int q = q0 + (int)threadIdx.x; q < q1; q += (int)blockDim.x) {
        double2 pa = pd2[2*q], pb = pd2[2*q+1];
        int4 dd = d4[q]; int4 ss = s4[q];
        fscat64(sf, base, dd.x, ss.x, pa.x);
        fscat64(sf, base, dd.y, ss.y, pa.y);
        fscat64(sf, base, dd.z, ss.z, pb.x);
        fscat64(sf, base, dd.w, ss.w, pb.y);
    }
    if (c == NC-1) {
        for (int e = (NQ<<2) + (int)threadIdx.x; e < E; e += (int)blockDim.x) {
            fscat64(sf, base, dst[e], src[e], pd[e]);
        }
    }
    __syncthreads();
    size_t sb = (size_t)(t * NC + c) * T_C;
    for (int i = threadIdx.x; i < T_C; i += blockDim.x) scratch[sb + i] = sf[i];
}

// K6: sum packed chunks, decode fields -> forces (fully overwrites output)
__global__ __launch_bounds__(256) void k6_pk64(
        const double* __restrict__ scratch, float* __restrict__ forces,
        int N, int NC)
{
    int n = blockIdx.x*blockDim.x + threadIdx.x;
    if (n >= N) return;
    int t = n / T_C; int off = n - t*T_C;
    const double* bp = scratch + ((size_t)t*NC)*T_C + off;
    double V = 0.0;
    for (int k = 0; k < NC; ++k) V += bp[(size_t)k*T_C];
    double h1 = rint(V * (1.0/PK_K1));
    double rem = V - h1 * PK_K1;
    double h2 = rint(rem * (1.0/PK_K2));
    double Z = rem - h2 * PK_K2;
    forces[3*n+0] = (float)(h1 * (1.0/(double)PK_Q));
    forces[3*n+1] = (float)(h2 * (1.0/(double)PK_Q));
    forces[3*n+2] = (float)Z;
}

// ============== FALLBACK PATH (atomic kernels, any ws_size) ==============

__global__ __launch_bounds__(256) void fb_pass1(
        const float* __restrict__ r, const int* __restrict__ dst,
        const int* __restrict__ n2g,
        const float* __restrict__ p_da, const float* __restrict__ p_dl,
        const float* __restrict__ p_ra, const float* __restrict__ p_rl,
        float* __restrict__ local_density, float* __restrict__ e_graph, int E)
{
    __shared__ float sbin[NG];
    if (threadIdx.x < NG) sbin[threadIdx.x] = 0.f;
    __syncthreads();
    const float Ad = softplus_f(*p_da), Ld = softplus_f(*p_dl);
    const float Ar = softplus_f(*p_ra), Lr = softplus_f(*p_rl);
    const int stride = gridDim.x * blockDim.x;
    for (int e = blockIdx.x*blockDim.x + threadIdx.x; e < E; e += stride) {
        float x = r[3*e], y = r[3*e+1], z = r[3*e+2];
        float bl = sqrtf(x*x + y*y + z*z);
        int de = dst[e];
        atomicAdd(&local_density[de], Ad*expf(-Ld*bl));
        atomicAdd(&sbin[n2g[de]], Ar*expf(-Lr*bl));
    }
    __syncthreads();
    if (threadIdx.x < NG) atomicAdd(&e_graph[threadIdx.x], sbin[threadIdx.x]);
}

__global__ __launch_bounds__(256) void fb_pass2(
        float* __restrict__ ld_g, const int* __restrict__ n2g,
        const float* __restrict__ p_ea, float* __restrict__ e_graph, int N)
{
    __shared__ float sbin[NG];
    if (threadIdx.x < NG) sbin[threadIdx.x] = 0.f;
    __syncthreads();
    const float Ae = softplus_f(*p_ea);
    const int stride = gridDim.x * blockDim.x;
    for (int n = blockIdx.x*blockDim.x + threadIdx.x; n < N; n += stride) {
        float l = ld_g[n];
        float s = sqrtf(fmaxf(l, 1e-12f));
        atomicAdd(&sbin[n2g[n]], -Ae*s);
        ld_g[n] = (l >= 1e-12f) ? (-0.5f*Ae/s) : 0.f;
    }
    __syncthreads();
    if (threadIdx.x < NG) atomicAdd(&e_graph[threadIdx.x], sbin[threadIdx.x]);
}

__global__ __launch_bounds__(256) void fb_pass3(
        const float* __restrict__ r, const int* __restrict__ src,
        const int* __restrict__ dst, const float* __restrict__ g,
        const float* __restrict__ p_da, const float* __restrict__ p_dl,
        const float* __restrict__ p_ra, const float* __restrict__ p_rl,
        float* __restrict__ forces, int E)
{
    const float Ad = softplus_f(*p_da), Ld = softplus_f(*p_dl);
    const float Ar = softplus_f(*p_ra), Lr = softplus_f(*p_rl);
    const int stride = gridDim.x * blockDim.x;
    for (int e = blockIdx.x*blockDim.x + threadIdx.x; e < E; e += stride) {
        float x = r[3*e], y = r[3*e+1], z = r[3*e+2];
        float bl = sqrtf(x*x + y*y + z*z);
        int de = dst[e], se = src[e];
        float dEdb = g[de]*(-Ld*Ad*expf(-Ld*bl)) - Lr*Ar*expf(-Lr*bl);
        float s = (bl > 0.f) ? dEdb/bl : 0.f;
        float fx = s*x, fy = s*y, fz = s*z;
        atomicAdd(&forces[3*de+0], -fx); atomicAdd(&forces[3*de+1], -fy); atomicAdd(&forces[3*de+2], -fz);
        atomicAdd(&forces[3*se+0],  fx); atomicAdd(&forces[3*se+1],  fy); atomicAdd(&forces[3*se+2],  fz);
    }
}

extern "C" void kernel_launch(void* const* d_in, const int* in_sizes, int n_in,
                              void* d_out, int out_size, void* d_ws, size_t ws_size,
                              hipStream_t stream) {
    const float* r    = (const float*)d_in[0];
    const int*   src  = (const int*)d_in[1];
    const int*   dst  = (const int*)d_in[2];
    const int*   n2g  = (const int*)d_in[3];
    const float* p_da = (const float*)d_in[4];
    const float* p_dl = (const float*)d_in[5];
    const float* p_ra = (const float*)d_in[6];
    const float* p_rl = (const float*)d_in[7];
    const float* p_ea = (const float*)d_in[8];

    const int E = in_sizes[1];
    const int N = in_sizes[3];

    float* e_graph = (float*)d_out;
    float* forces  = (float*)d_out + NG;

    const int E4 = (E + 3) & ~3;
    const int NT_D = (N + T_N - 1) / T_N;   // 3
    const int NT_C = (N + T_C - 1) / T_C;   // 5

    const size_t wsf_n    = ws_size / 4;
    const size_t n_ld     = ((size_t)N + 63) & ~(size_t)63;
    const size_t off_edge = n_ld;                              // 8B-aligned (n_ld 64-aligned)
    const size_t off_scr  = off_edge + (size_t)2 * (size_t)E4; // dens f32 / pd f64 overlay

    long avail = (long)wsf_n - (long)off_scr;
    int NC_D = 0, NC_F = 0;
    if (avail > 0) {
        long cd = avail / ((long)NT_D * T_N);        // floats per density chunk
        long cf = avail / ((long)NT_C * T_C * 2);    // floats per packed force chunk
        NC_D = (int)(cd > 80 ? 80 : cd);
        NC_F = (int)(cf > 48 ? 48 : cf);
        if (NC_D >= 8) NC_D &= ~7;
        if (NC_F >= 8) NC_F &= ~7;
    }

    const int NQ = E >> 2;
    int ge = (NQ + 255) / 256; if (ge > 2048) ge = 2048;

    if (NC_D >= 1 && NC_F >= 1) {
        float*  ld_g     = (float*)d_ws;
        float*  edgebuf  = (float*)d_ws + off_edge;   // dens[E4] f32, later pd[E] f64
        double* pd       = (double*)edgebuf;
        float*  scratchf = (float*)d_ws + off_scr;
        double* scratchd = (double*)scratchf;

        hipMemsetAsync(d_out, 0, NG * sizeof(float), stream);

        k1_dens<<<ge, 256, 0, stream>>>(r, p_da, p_dl, edgebuf, E);
        k2_dens_tiles<<<NT_D * NC_D, 512, 0, stream>>>(edgebuf, dst, scratchf,
                                                       E, NT_D, NC_D);
        k3_node<<<(N + 255) / 256, 256, 0, stream>>>(scratchf, n2g, p_ea,
                                                     ld_g, e_graph, N, NC_D);
        k4_pd8<<<ge, 256, 0, stream>>>(r, dst, n2g, ld_g, p_da, p_dl, p_ra, p_rl,
                                       pd, e_graph, E);
        k5_pk64<<<NT_C * NC_F, 512, 0, stream>>>(pd, src, dst,
                                                 scratchd, E, NT_C, NC_F);
        k6_pk64<<<(N + 255) / 256, 256, 0, stream>>>(scratchd, forces, N, NC_F);
    } else {
        float* ld_g = (float*)d_ws;
        hipMemsetAsync(d_out, 0, (size_t)out_size * sizeof(float), stream);
        hipMemsetAsync(d_ws, 0, (size_t)N * sizeof(float), stream);
        int geb = (E + 255) / 256; if (geb > 2048) geb = 2048;
        fb_pass1<<<geb, 256, 0, stream>>>(r, dst, n2g, p_da, p_dl, p_ra, p_rl,
                                          ld_g, e_graph, E);
        fb_pass2<<<(N + 255) / 256, 256, 0, stream>>>(ld_g, n2g, p_ea, e_graph, N);
        fb_pass3<<<geb, 256, 0, stream>>>(r, src, dst, ld_g, p_da, p_dl, p_ra, p_rl,
                                          forces, E);
    }
}

// Round 10
// 244.281 us; speedup vs baseline: 2.8904x; 2.8904x over previous
//
#include <hip/hip_runtime.h>
#include <math.h>

#define NG 32
#define T_N 40704           // density tile: 40704 floats = 159.0 KB LDS
#define T_C 20352           // force tile: 20352 packed doubles = 159.0 KB LDS

// f64 packing constants: p = rint(32 fx)*2^33 + rint(32 fy)*2^17 + fz
#define PK_Q   32.0f
#define PK_K1  8589934592.0   // 2^33
#define PK_K2  131072.0       // 2^17

__device__ __forceinline__ float softplus_f(float x) {
    return (x > 0.f) ? (x + log1pf(expf(-x))) : log1pf(expf(x));
}

__device__ __forceinline__ void lds_fadd64(double* p, double v) {
#if defined(__HIP_PLATFORM_AMD__) || defined(__AMDGCN__)
    unsafeAtomicAdd(p, v);      // ds_add_f64 on gfx90a+
#else
    atomicAdd(p, v);
#endif
}

// gid -> (tile t, chunk c) with all tiles of a chunk on one XCD (gid%8 == c%8),
// assuming round-robin workgroup->XCD dispatch. Requires NC % 8 == 0; else identity.
__device__ __forceinline__ void map_tc(int gid, int NT, int NC, int* t, int* c) {
    if ((NC & 7) == 0) {
        int x = gid & 7, s = gid >> 3;
        *t = s % NT;
        *c = (s / NT) * 8 + x;
    } else {
        *t = gid / NC;
        *c = gid - (*t) * NC;
    }
}

// K1: pure streaming map: r -> dens
__global__ __launch_bounds__(256) void k1_dens(
        const float* __restrict__ r,
        const float* __restrict__ p_da, const float* __restrict__ p_dl,
        float* __restrict__ dens_arr, int E)
{
    const float Ad = softplus_f(*p_da), Ld = softplus_f(*p_dl);
    const float4* r4 = (const float4*)r;
    float4* dens4 = (float4*)dens_arr;
    const int NQ = E >> 2;
    const int stride = gridDim.x * blockDim.x;
    for (int q = blockIdx.x*blockDim.x + threadIdx.x; q < NQ; q += stride) {
        float4 a = r4[3*q], b = r4[3*q+1], c = r4[3*q+2];
        float bl0 = sqrtf(a.x*a.x + a.y*a.y + a.z*a.z);
        float bl1 = sqrtf(a.w*a.w + b.x*b.x + b.y*b.y);
        float bl2 = sqrtf(b.z*b.z + b.w*b.w + c.x*c.x);
        float bl3 = sqrtf(c.y*c.y + c.z*c.z + c.w*c.w);
        float4 dv = { Ad*expf(-Ld*bl0), Ad*expf(-Ld*bl1),
                      Ad*expf(-Ld*bl2), Ad*expf(-Ld*bl3) };
        dens4[q] = dv;
    }
    for (int e = (NQ<<2) + blockIdx.x*blockDim.x + threadIdx.x; e < E; e += stride) {
        float x = r[3*e], y = r[3*e+1], z = r[3*e+2];
        float bl = sqrtf(x*x + y*y + z*z);
        dens_arr[e] = Ad*expf(-Ld*bl);
    }
}

// K2: density scatter into 159KB LDS node tile (proven shape)
__global__ __launch_bounds__(512) void k2_dens_tiles(
        const float* __restrict__ dens_arr, const int* __restrict__ dst,
        float* __restrict__ scratch, int E, int NT, int NC)
{
    __shared__ float sd[T_N];
    int t, k;
    map_tc(blockIdx.x, NT, NC, &t, &k);
    const int base = t * T_N;
    for (int i = threadIdx.x; i < T_N; i += blockDim.x) sd[i] = 0.f;
    __syncthreads();
    const int NQ = E >> 2;
    const int cq = (NQ + NC - 1) / NC;
    const int q0 = k*cq;
    const int q1 = (q0 + cq < NQ) ? (q0 + cq) : NQ;
    const float4* dens4 = (const float4*)dens_arr;
    const int4*   d4 = (const int4*)dst;
    for (int q = q0 + (int)threadIdx.x; q < q1; q += (int)blockDim.x) {
        float4 dv = dens4[q]; int4 dd = d4[q];
        unsigned l;
        l = (unsigned)(dd.x - base); if (l < T_N) atomicAdd(&sd[l], dv.x);
        l = (unsigned)(dd.y - base); if (l < T_N) atomicAdd(&sd[l], dv.y);
        l = (unsigned)(dd.z - base); if (l < T_N) atomicAdd(&sd[l], dv.z);
        l = (unsigned)(dd.w - base); if (l < T_N) atomicAdd(&sd[l], dv.w);
    }
    if (k == NC-1) {
        for (int e = (NQ<<2) + (int)threadIdx.x; e < E; e += (int)blockDim.x) {
            unsigned l = (unsigned)(dst[e] - base);
            if (l < T_N) atomicAdd(&sd[l], dens_arr[e]);
        }
    }
    __syncthreads();
    size_t sb = (size_t)(t * NC + k) * T_N;
    for (int i = threadIdx.x; i < T_N; i += blockDim.x) scratch[sb + i] = sd[i];
}

// K3: reduce density chunks; embedding energy -> bins; g = dE/d(local_density)
__global__ __launch_bounds__(256) void k3_node(
        const float* __restrict__ scratch, const int* __restrict__ n2g,
        const float* __restrict__ p_ea,
        float* __restrict__ g_out, float* __restrict__ e_graph, int N, int NC)
{
    __shared__ float sbin[NG];
    if (threadIdx.x < NG) sbin[threadIdx.x] = 0.f;
    __syncthreads();
    const float Ae = softplus_f(*p_ea);
    int n = blockIdx.x*blockDim.x + threadIdx.x;
    if (n < N) {
        int t = n / T_N; int off = n - t*T_N;
        const float* bp = scratch + ((size_t)t*NC)*T_N + off;
        float l = 0.f;
        for (int k = 0; k < NC; ++k) l += bp[(size_t)k*T_N];
        float s = sqrtf(fmaxf(l, 1e-12f));
        atomicAdd(&sbin[n2g[n]], -Ae*s);
        g_out[n] = (l >= 1e-12f) ? (-0.5f*Ae/s) : 0.f;
    }
    __syncthreads();
    if (threadIdx.x < NG) atomicAdd(&e_graph[threadIdx.x], sbin[threadIdx.x]);
}

// pack 3 force comps into one f64: rint(32x)*2^33 + rint(32y)*2^17 + z
__device__ __forceinline__ double pk3(float fx, float fy, float fz) {
    double hx = (double)rintf(fx * PK_Q);
    double hy = (double)rintf(fy * PK_Q);
    return hx * PK_K1 + hy * PK_K2 + (double)fz;
}

// K4: per-edge dE/dr packed to f64 pd[e]; repulsive -> 8x bank-staggered replica
// bins, LDS-reduced and PLAIN-STORED to per-block partials (NO global atomics).
#define RSTRIDE 33           // replica k of graph g at slot g + k*33 -> bank (g+k)&31
__global__ __launch_bounds__(256) void k4_pd(
        const float* __restrict__ r, const int* __restrict__ dst,
        const int* __restrict__ n2g, const float* __restrict__ g,
        const float* __restrict__ p_da, const float* __restrict__ p_dl,
        const float* __restrict__ p_ra, const float* __restrict__ p_rl,
        double* __restrict__ pd, float* __restrict__ bins_out, int E)
{
    __shared__ float sbin[RSTRIDE*8];
    for (int i = threadIdx.x; i < RSTRIDE*8; i += blockDim.x) sbin[i] = 0.f;
    __syncthreads();
    const float Ad = softplus_f(*p_da), Ld = softplus_f(*p_dl);
    const float Ar = softplus_f(*p_ra), Lr = softplus_f(*p_rl);
    const float4* r4 = (const float4*)r;
    const int4*   d4 = (const int4*)dst;
    const int NQ = E >> 2;
    const int stride = gridDim.x * blockDim.x;
    const int rep_slot = ((int)threadIdx.x & 7) * RSTRIDE;
    for (int q = blockIdx.x*blockDim.x + threadIdx.x; q < NQ; q += stride) {
        float4 a = r4[3*q], b = r4[3*q+1], c = r4[3*q+2];
        int4 dd = d4[q];
        float g0 = g[dd.x], g1 = g[dd.y], g2 = g[dd.z], g3 = g[dd.w];
        int b0 = n2g[dd.x], b1 = n2g[dd.y], b2 = n2g[dd.z], b3 = n2g[dd.w];
        float bl0 = sqrtf(a.x*a.x + a.y*a.y + a.z*a.z);
        float bl1 = sqrtf(a.w*a.w + b.x*b.x + b.y*b.y);
        float bl2 = sqrtf(b.z*b.z + b.w*b.w + c.x*c.x);
        float bl3 = sqrtf(c.y*c.y + c.z*c.z + c.w*c.w);
        float rep0 = Ar*expf(-Lr*bl0), rep1 = Ar*expf(-Lr*bl1);
        float rep2 = Ar*expf(-Lr*bl2), rep3 = Ar*expf(-Lr*bl3);
        float de0 = g0*(-Ld*Ad*expf(-Ld*bl0)) - Lr*rep0;
        float de1 = g1*(-Ld*Ad*expf(-Ld*bl1)) - Lr*rep1;
        float de2 = g2*(-Ld*Ad*expf(-Ld*bl2)) - Lr*rep2;
        float de3 = g3*(-Ld*Ad*expf(-Ld*bl3)) - Lr*rep3;
        float s0 = (bl0 > 0.f) ? de0/bl0 : 0.f;
        float s1 = (bl1 > 0.f) ? de1/bl1 : 0.f;
        float s2 = (bl2 > 0.f) ? de2/bl2 : 0.f;
        float s3 = (bl3 > 0.f) ? de3/bl3 : 0.f;
        pd[4*q+0] = pk3(s0*a.x, s0*a.y, s0*a.z);
        pd[4*q+1] = pk3(s1*a.w, s1*b.x, s1*b.y);
        pd[4*q+2] = pk3(s2*b.z, s2*b.w, s2*c.x);
        pd[4*q+3] = pk3(s3*c.y, s3*c.z, s3*c.w);
        atomicAdd(&sbin[b0 + rep_slot], rep0);
        atomicAdd(&sbin[b1 + rep_slot], rep1);
        atomicAdd(&sbin[b2 + rep_slot], rep2);
        atomicAdd(&sbin[b3 + rep_slot], rep3);
    }
    for (int e = (NQ<<2) + blockIdx.x*blockDim.x + threadIdx.x; e < E; e += stride) {
        float x = r[3*e], y = r[3*e+1], z = r[3*e+2];
        float bl = sqrtf(x*x + y*y + z*z);
        int de = dst[e];
        float rep = Ar*expf(-Lr*bl);
        float dEdb = g[de]*(-Ld*Ad*expf(-Ld*bl)) - Lr*rep;
        float s = (bl > 0.f) ? dEdb/bl : 0.f;
        pd[e] = pk3(s*x, s*y, s*z);
        atomicAdd(&sbin[n2g[de] + rep_slot], rep);
    }
    __syncthreads();
    if (threadIdx.x < NG) {
        float sum = 0.f;
        #pragma unroll
        for (int k = 0; k < 8; ++k) sum += sbin[threadIdx.x + k*RSTRIDE];
        bins_out[(size_t)blockIdx.x * NG + threadIdx.x] = sum;
    }
}

// K7: reduce per-block bin partials (NB x 32) -> e_graph (single block, no atomics)
__global__ __launch_bounds__(1024) void k7_bins(
        const float* __restrict__ bins, float* __restrict__ e_graph, int NB)
{
    __shared__ float sacc[1024];
    const int t = threadIdx.x;
    float a = 0.f;
    const int total = NB * NG;
    for (int i = t; i < total; i += 1024) a += bins[i];   // stride 1024 ≡ 0 mod 32
    sacc[t] = a;
    __syncthreads();
    for (int s = 512; s >= NG; s >>= 1) {
        if (t < s) sacc[t] += sacc[t + s];
        __syncthreads();
    }
    if (t < NG) e_graph[t] += sacc[t];
}

__device__ __forceinline__ void fscat64(double* sf, int base, int d, int s, double p) {
    unsigned ld = (unsigned)(d - base);
    if (ld < T_C) lds_fadd64(&sf[ld], -p);
    unsigned ls = (unsigned)(s - base);
    if (ls < T_C) lds_fadd64(&sf[ls],  p);
}

// K5: force scatter; ONE packed f64 LDS atomic per taken endpoint (pd precomputed)
__global__ __launch_bounds__(512) void k5_pk64(
        const double* __restrict__ pd, const int* __restrict__ src,
        const int* __restrict__ dst,
        double* __restrict__ scratch, int E, int NT, int NC)
{
    __shared__ double sf[T_C];
    int t, c;
    map_tc(blockIdx.x, NT, NC, &t, &c);
    const int base = t * T_C;
    for (int i = threadIdx.x; i < T_C; i += blockDim.x) sf[i] = 0.0;
    __syncthreads();
    const int NQ = E >> 2;
    const int cq = (NQ + NC - 1) / NC;
    const int q0 = c*cq;
    const int q1 = (q0 + cq < NQ) ? (q0 + cq) : NQ;
    const double2* pd2 = (const double2*)pd;
    const int4* d4 = (const int4*)dst;
    const int4* s4 = (const int4*)src;
    for (int q = q0 + (int)threadIdx.x; q < q1; q += (int)blockDim.x) {
        double2 pa = pd2[2*q], pb = pd2[2*q+1];
        int4 dd = d4[q]; int4 ss = s4[q];
        fscat64(sf, base, dd.x, ss.x, pa.x);
        fscat64(sf, base, dd.y, ss.y, pa.y);
        fscat64(sf, base, dd.z, ss.z, pb.x);
        fscat64(sf, base, dd.w, ss.w, pb.y);
    }
    if (c == NC-1) {
        for (int e = (NQ<<2) + (int)threadIdx.x; e < E; e += (int)blockDim.x) {
            fscat64(sf, base, dst[e], src[e], pd[e]);
        }
    }
    __syncthreads();
    size_t sb = (size_t)(t * NC + c) * T_C;
    for (int i = threadIdx.x; i < T_C; i += blockDim.x) scratch[sb + i] = sf[i];
}

// K6: sum packed chunks, decode fields -> forces (fully overwrites output)
__global__ __launch_bounds__(256) void k6_pk64(
        const double* __restrict__ scratch, float* __restrict__ forces,
        int N, int NC)
{
    int n = blockIdx.x*blockDim.x + threadIdx.x;
    if (n >= N) return;
    int t = n / T_C; int off = n - t*T_C;
    const double* bp = scratch + ((size_t)t*NC)*T_C + off;
    double V = 0.0;
    for (int k = 0; k < NC; ++k) V += bp[(size_t)k*T_C];
    double h1 = rint(V * (1.0/PK_K1));
    double rem = V - h1 * PK_K1;
    double h2 = rint(rem * (1.0/PK_K2));
    double Z = rem - h2 * PK_K2;
    forces[3*n+0] = (float)(h1 * (1.0/(double)PK_Q));
    forces[3*n+1] = (float)(h2 * (1.0/(double)PK_Q));
    forces[3*n+2] = (float)Z;
}

// ============== FALLBACK PATH (atomic kernels, any ws_size) ==============

__global__ __launch_bounds__(256) void fb_pass1(
        const float* __restrict__ r, const int* __restrict__ dst,
        const int* __restrict__ n2g,
        const float* __restrict__ p_da, const float* __restrict__ p_dl,
        const float* __restrict__ p_ra, const float* __restrict__ p_rl,
        float* __restrict__ local_density, float* __restrict__ e_graph, int E)
{
    __shared__ float sbin[NG];
    if (threadIdx.x < NG) sbin[threadIdx.x] = 0.f;
    __syncthreads();
    const float Ad = softplus_f(*p_da), Ld = softplus_f(*p_dl);
    const float Ar = softplus_f(*p_ra), Lr = softplus_f(*p_rl);
    const int stride = gridDim.x * blockDim.x;
    for (int e = blockIdx.x*blockDim.x + threadIdx.x; e < E; e += stride) {
        float x = r[3*e], y = r[3*e+1], z = r[3*e+2];
        float bl = sqrtf(x*x + y*y + z*z);
        int de = dst[e];
        atomicAdd(&local_density[de], Ad*expf(-Ld*bl));
        atomicAdd(&sbin[n2g[de]], Ar*expf(-Lr*bl));
    }
    __syncthreads();
    if (threadIdx.x < NG) atomicAdd(&e_graph[threadIdx.x], sbin[threadIdx.x]);
}

__global__ __launch_bounds__(256) void fb_pass2(
        float* __restrict__ ld_g, const int* __restrict__ n2g,
        const float* __restrict__ p_ea, float* __restrict__ e_graph, int N)
{
    __shared__ float sbin[NG];
    if (threadIdx.x < NG) sbin[threadIdx.x] = 0.f;
    __syncthreads();
    const float Ae = softplus_f(*p_ea);
    const int stride = gridDim.x * blockDim.x;
    for (int n = blockIdx.x*blockDim.x + threadIdx.x; n < N; n += stride) {
        float l = ld_g[n];
        float s = sqrtf(fmaxf(l, 1e-12f));
        atomicAdd(&sbin[n2g[n]], -Ae*s);
        ld_g[n] = (l >= 1e-12f) ? (-0.5f*Ae/s) : 0.f;
    }
    __syncthreads();
    if (threadIdx.x < NG) atomicAdd(&e_graph[threadIdx.x], sbin[threadIdx.x]);
}

__global__ __launch_bounds__(256) void fb_pass3(
        const float* __restrict__ r, const int* __restrict__ src,
        const int* __restrict__ dst, const float* __restrict__ g,
        const float* __restrict__ p_da, const float* __restrict__ p_dl,
        const float* __restrict__ p_ra, const float* __restrict__ p_rl,
        float* __restrict__ forces, int E)
{
    const float Ad = softplus_f(*p_da), Ld = softplus_f(*p_dl);
    const float Ar = softplus_f(*p_ra), Lr = softplus_f(*p_rl);
    const int stride = gridDim.x * blockDim.x;
    for (int e = blockIdx.x*blockDim.x + threadIdx.x; e < E; e += stride) {
        float x = r[3*e], y = r[3*e+1], z = r[3*e+2];
        float bl = sqrtf(x*x + y*y + z*z);
        int de = dst[e], se = src[e];
        float dEdb = g[de]*(-Ld*Ad*expf(-Ld*bl)) - Lr*Ar*expf(-Lr*bl);
        float s = (bl > 0.f) ? dEdb/bl : 0.f;
        float fx = s*x, fy = s*y, fz = s*z;
        atomicAdd(&forces[3*de+0], -fx); atomicAdd(&forces[3*de+1], -fy); atomicAdd(&forces[3*de+2], -fz);
        atomicAdd(&forces[3*se+0],  fx); atomicAdd(&forces[3*se+1],  fy); atomicAdd(&forces[3*se+2],  fz);
    }
}

extern "C" void kernel_launch(void* const* d_in, const int* in_sizes, int n_in,
                              void* d_out, int out_size, void* d_ws, size_t ws_size,
                              hipStream_t stream) {
    const float* r    = (const float*)d_in[0];
    const int*   src  = (const int*)d_in[1];
    const int*   dst  = (const int*)d_in[2];
    const int*   n2g  = (const int*)d_in[3];
    const float* p_da = (const float*)d_in[4];
    const float* p_dl = (const float*)d_in[5];
    const float* p_ra = (const float*)d_in[6];
    const float* p_rl = (const float*)d_in[7];
    const float* p_ea = (const float*)d_in[8];

    const int E = in_sizes[1];
    const int N = in_sizes[3];

    float* e_graph = (float*)d_out;
    float* forces  = (float*)d_out + NG;

    const int E4 = (E + 3) & ~3;
    const int NT_D = (N + T_N - 1) / T_N;   // 3
    const int NT_C = (N + T_C - 1) / T_C;   // 5

    const int NQ = E >> 2;
    int ge = (NQ + 255) / 256; if (ge > 2048) ge = 2048;

    const size_t wsf_n    = ws_size / 4;
    const size_t n_ld     = ((size_t)N + 63) & ~(size_t)63;
    const size_t off_edge = n_ld;                               // 8B-aligned (n_ld 64-aligned)
    const size_t off_bins = off_edge + (size_t)2 * (size_t)E4;  // dens f32 / pd f64 overlay
    const size_t off_scr  = off_bins + ((size_t)ge * NG + 63 & ~(size_t)63);

    long avail = (long)wsf_n - (long)off_scr;
    int NC_D = 0, NC_F = 0;
    if (avail > 0) {
        long cd = avail / ((long)NT_D * T_N);        // floats per density chunk
        long cf = avail / ((long)NT_C * T_C * 2);    // floats per packed force chunk
        NC_D = (int)(cd > 80 ? 80 : cd);
        NC_F = (int)(cf > 48 ? 48 : cf);
        if (NC_D >= 8) NC_D &= ~7;
        if (NC_F >= 8) NC_F &= ~7;
    }

    if (NC_D >= 1 && NC_F >= 1) {
        float*  ld_g     = (float*)d_ws;
        float*  edgebuf  = (float*)d_ws + off_edge;   // dens[E4] f32, later pd[E] f64
        double* pd       = (double*)edgebuf;
        float*  bins     = (float*)d_ws + off_bins;   // ge x 32 partials
        float*  scratchf = (float*)d_ws + off_scr;
        double* scratchd = (double*)scratchf;

        hipMemsetAsync(d_out, 0, NG * sizeof(float), stream);

        k1_dens<<<ge, 256, 0, stream>>>(r, p_da, p_dl, edgebuf, E);
        k2_dens_tiles<<<NT_D * NC_D, 512, 0, stream>>>(edgebuf, dst, scratchf,
                                                       E, NT_D, NC_D);
        k3_node<<<(N + 255) / 256, 256, 0, stream>>>(scratchf, n2g, p_ea,
                                                     ld_g, e_graph, N, NC_D);
        k4_pd<<<ge, 256, 0, stream>>>(r, dst, n2g, ld_g, p_da, p_dl, p_ra, p_rl,
                                      pd, bins, E);
        k7_bins<<<1, 1024, 0, stream>>>(bins, e_graph, ge);
        k5_pk64<<<NT_C * NC_F, 512, 0, stream>>>(pd, src, dst,
                                                 scratchd, E, NT_C, NC_F);
        k6_pk64<<<(N + 255) / 256, 256, 0, stream>>>(scratchd, forces, N, NC_F);
    } else {
        float* ld_g = (float*)d_ws;
        hipMemsetAsync(d_out, 0, (size_t)out_size * sizeof(float), stream);
        hipMemsetAsync(d_ws, 0, (size_t)N * sizeof(float), stream);
        int geb = (E + 255) / 256; if (geb > 2048) geb = 2048;
        fb_pass1<<<geb, 256, 0, stream>>>(r, dst, n2g, p_da, p_dl, p_ra, p_rl,
                                          ld_g, e_graph, E);
        fb_pass2<<<(N + 255) / 256, 256, 0, stream>>>(ld_g, n2g, p_ea, e_graph, N);
        fb_pass3<<<geb, 256, 0, stream>>>(r, src, dst, ld_g, p_da, p_dl, p_ra, p_rl,
                                          forces, E);
    }
}

// Round 11
// 225.543 us; speedup vs baseline: 3.1306x; 1.0831x over previous
//
#include <hip/hip_runtime.h>
#include <math.h>

#define NG 32
#define T_N 40704           // density tile: 40704 floats = 159.0 KB LDS
#define T_C 20352           // force tile: 20352 packed doubles = 159.0 KB LDS

// f64 packing constants: p = rint(32 fx)*2^33 + rint(32 fy)*2^17 + fz
#define PK_Q   32.0f
#define PK_K1  8589934592.0   // 2^33
#define PK_K2  131072.0       // 2^17

__device__ __forceinline__ float softplus_f(float x) {
    return (x > 0.f) ? (x + log1pf(expf(-x))) : log1pf(expf(x));
}

__device__ __forceinline__ void lds_fadd64(double* p, double v) {
#if defined(__HIP_PLATFORM_AMD__) || defined(__AMDGCN__)
    unsafeAtomicAdd(p, v);      // ds_add_f64 on gfx90a+
#else
    atomicAdd(p, v);
#endif
}

// gid -> (tile t, chunk c) with all tiles of a chunk on one XCD (gid%8 == c%8),
// assuming round-robin workgroup->XCD dispatch. Requires NC % 8 == 0; else identity.
__device__ __forceinline__ void map_tc(int gid, int NT, int NC, int* t, int* c) {
    if ((NC & 7) == 0) {
        int x = gid & 7, s = gid >> 3;
        *t = s % NT;
        *c = (s / NT) * 8 + x;
    } else {
        *t = gid / NC;
        *c = gid - (*t) * NC;
    }
}

// K1: pure streaming map: r -> dens
__global__ __launch_bounds__(256) void k1_dens(
        const float* __restrict__ r,
        const float* __restrict__ p_da, const float* __restrict__ p_dl,
        float* __restrict__ dens_arr, int E)
{
    const float Ad = softplus_f(*p_da), Ld = softplus_f(*p_dl);
    const float4* r4 = (const float4*)r;
    float4* dens4 = (float4*)dens_arr;
    const int NQ = E >> 2;
    const int stride = gridDim.x * blockDim.x;
    for (int q = blockIdx.x*blockDim.x + threadIdx.x; q < NQ; q += stride) {
        float4 a = r4[3*q], b = r4[3*q+1], c = r4[3*q+2];
        float bl0 = sqrtf(a.x*a.x + a.y*a.y + a.z*a.z);
        float bl1 = sqrtf(a.w*a.w + b.x*b.x + b.y*b.y);
        float bl2 = sqrtf(b.z*b.z + b.w*b.w + c.x*c.x);
        float bl3 = sqrtf(c.y*c.y + c.z*c.z + c.w*c.w);
        float4 dv = { Ad*expf(-Ld*bl0), Ad*expf(-Ld*bl1),
                      Ad*expf(-Ld*bl2), Ad*expf(-Ld*bl3) };
        dens4[q] = dv;
    }
    for (int e = (NQ<<2) + blockIdx.x*blockDim.x + threadIdx.x; e < E; e += stride) {
        float x = r[3*e], y = r[3*e+1], z = r[3*e+2];
        float bl = sqrtf(x*x + y*y + z*z);
        dens_arr[e] = Ad*expf(-Ld*bl);
    }
}

// K2: density scatter into 159KB LDS node tile (proven shape)
__global__ __launch_bounds__(512) void k2_dens_tiles(
        const float* __restrict__ dens_arr, const int* __restrict__ dst,
        float* __restrict__ scratch, int E, int NT, int NC)
{
    __shared__ float sd[T_N];
    int t, k;
    map_tc(blockIdx.x, NT, NC, &t, &k);
    const int base = t * T_N;
    for (int i = threadIdx.x; i < T_N; i += blockDim.x) sd[i] = 0.f;
    __syncthreads();
    const int NQ = E >> 2;
    const int cq = (NQ + NC - 1) / NC;
    const int q0 = k*cq;
    const int q1 = (q0 + cq < NQ) ? (q0 + cq) : NQ;
    const float4* dens4 = (const float4*)dens_arr;
    const int4*   d4 = (const int4*)dst;
    for (int q = q0 + (int)threadIdx.x; q < q1; q += (int)blockDim.x) {
        float4 dv = dens4[q]; int4 dd = d4[q];
        unsigned l;
        l = (unsigned)(dd.x - base); if (l < T_N) atomicAdd(&sd[l], dv.x);
        l = (unsigned)(dd.y - base); if (l < T_N) atomicAdd(&sd[l], dv.y);
        l = (unsigned)(dd.z - base); if (l < T_N) atomicAdd(&sd[l], dv.z);
        l = (unsigned)(dd.w - base); if (l < T_N) atomicAdd(&sd[l], dv.w);
    }
    if (k == NC-1) {
        for (int e = (NQ<<2) + (int)threadIdx.x; e < E; e += (int)blockDim.x) {
            unsigned l = (unsigned)(dst[e] - base);
            if (l < T_N) atomicAdd(&sd[l], dens_arr[e]);
        }
    }
    __syncthreads();
    size_t sb = (size_t)(t * NC + k) * T_N;
    for (int i = threadIdx.x; i < T_N; i += blockDim.x) scratch[sb + i] = sd[i];
}

// K3: reduce density chunks; embedding energy -> bins;
// g_out = dE/d(local_density) with graph id ENCODED in low 5 mantissa bits.
__global__ __launch_bounds__(256) void k3_node(
        const float* __restrict__ scratch, const int* __restrict__ n2g,
        const float* __restrict__ p_ea,
        float* __restrict__ g_out, float* __restrict__ e_graph, int N, int NC)
{
    __shared__ float sbin[NG];
    if (threadIdx.x < NG) sbin[threadIdx.x] = 0.f;
    __syncthreads();
    const float Ae = softplus_f(*p_ea);
    int n = blockIdx.x*blockDim.x + threadIdx.x;
    if (n < N) {
        int t = n / T_N; int off = n - t*T_N;
        const float* bp = scratch + ((size_t)t*NC)*T_N + off;
        float l = 0.f;
        for (int k = 0; k < NC; ++k) l += bp[(size_t)k*T_N];
        float s = sqrtf(fmaxf(l, 1e-12f));
        int gi = n2g[n];
        atomicAdd(&sbin[gi], -Ae*s);
        float gval = (l >= 1e-12f) ? (-0.5f*Ae/s) : 0.f;
        unsigned gb = (__float_as_uint(gval) & ~31u) | (unsigned)gi;
        g_out[n] = __uint_as_float(gb);     // <= 31 ulp perturbation (~2e-6 rel)
    }
    __syncthreads();
    if (threadIdx.x < NG) atomicAdd(&e_graph[threadIdx.x], sbin[threadIdx.x]);
}

// pack 3 force comps into one f64: rint(32x)*2^33 + rint(32y)*2^17 + z
__device__ __forceinline__ double pk3(float fx, float fy, float fz) {
    double hx = (double)rintf(fx * PK_Q);
    double hy = (double)rintf(fy * PK_Q);
    return hx * PK_K1 + hy * PK_K2 + (double)fz;
}

// K4: per-edge dE/dr packed to f64 pd[e]; repulsive -> 8x bank-staggered replica
// bins, LDS-reduced and PLAIN-STORED to per-block partials (NO global atomics).
// ONE gather per endpoint: g_enc carries both g and graph id.
#define RSTRIDE 33           // replica k of graph g at slot g + k*33 -> bank (g+k)&31
__global__ __launch_bounds__(256) void k4_pd(
        const float* __restrict__ r, const int* __restrict__ dst,
        const float* __restrict__ g_enc,
        const float* __restrict__ p_da, const float* __restrict__ p_dl,
        const float* __restrict__ p_ra, const float* __restrict__ p_rl,
        double* __restrict__ pd, float* __restrict__ bins_out, int E)
{
    __shared__ float sbin[RSTRIDE*8];
    for (int i = threadIdx.x; i < RSTRIDE*8; i += blockDim.x) sbin[i] = 0.f;
    __syncthreads();
    const float Ad = softplus_f(*p_da), Ld = softplus_f(*p_dl);
    const float Ar = softplus_f(*p_ra), Lr = softplus_f(*p_rl);
    const float nLdAd = -Ld*Ad;
    const float4* r4 = (const float4*)r;
    const int4*   d4 = (const int4*)dst;
    double2* pd2 = (double2*)pd;
    const int NQ = E >> 2;
    const int stride = gridDim.x * blockDim.x;
    const int rep_slot = ((int)threadIdx.x & 7) * RSTRIDE;
    for (int q = blockIdx.x*blockDim.x + threadIdx.x; q < NQ; q += stride) {
        float4 a = r4[3*q], b = r4[3*q+1], c = r4[3*q+2];
        int4 dd = d4[q];
        float g0 = g_enc[dd.x], g1 = g_enc[dd.y], g2 = g_enc[dd.z], g3 = g_enc[dd.w];
        int b0 = __float_as_uint(g0) & 31, b1 = __float_as_uint(g1) & 31;
        int b2 = __float_as_uint(g2) & 31, b3 = __float_as_uint(g3) & 31;
        float bl0 = sqrtf(a.x*a.x + a.y*a.y + a.z*a.z);
        float bl1 = sqrtf(a.w*a.w + b.x*b.x + b.y*b.y);
        float bl2 = sqrtf(b.z*b.z + b.w*b.w + c.x*c.x);
        float bl3 = sqrtf(c.y*c.y + c.z*c.z + c.w*c.w);
        float rep0 = Ar*expf(-Lr*bl0), rep1 = Ar*expf(-Lr*bl1);
        float rep2 = Ar*expf(-Lr*bl2), rep3 = Ar*expf(-Lr*bl3);
        float de0 = g0*(nLdAd*expf(-Ld*bl0)) - Lr*rep0;
        float de1 = g1*(nLdAd*expf(-Ld*bl1)) - Lr*rep1;
        float de2 = g2*(nLdAd*expf(-Ld*bl2)) - Lr*rep2;
        float de3 = g3*(nLdAd*expf(-Ld*bl3)) - Lr*rep3;
        float s0 = (bl0 > 0.f) ? de0/bl0 : 0.f;
        float s1 = (bl1 > 0.f) ? de1/bl1 : 0.f;
        float s2 = (bl2 > 0.f) ? de2/bl2 : 0.f;
        float s3 = (bl3 > 0.f) ? de3/bl3 : 0.f;
        double2 o0 = { pk3(s0*a.x, s0*a.y, s0*a.z), pk3(s1*a.w, s1*b.x, s1*b.y) };
        double2 o1 = { pk3(s2*b.z, s2*b.w, s2*c.x), pk3(s3*c.y, s3*c.z, s3*c.w) };
        pd2[2*q]   = o0;
        pd2[2*q+1] = o1;
        atomicAdd(&sbin[b0 + rep_slot], rep0);
        atomicAdd(&sbin[b1 + rep_slot], rep1);
        atomicAdd(&sbin[b2 + rep_slot], rep2);
        atomicAdd(&sbin[b3 + rep_slot], rep3);
    }
    for (int e = (NQ<<2) + blockIdx.x*blockDim.x + threadIdx.x; e < E; e += stride) {
        float x = r[3*e], y = r[3*e+1], z = r[3*e+2];
        float bl = sqrtf(x*x + y*y + z*z);
        float ge = g_enc[dst[e]];
        int bg = __float_as_uint(ge) & 31;
        float rep = Ar*expf(-Lr*bl);
        float dEdb = ge*(nLdAd*expf(-Ld*bl)) - Lr*rep;
        float s = (bl > 0.f) ? dEdb/bl : 0.f;
        pd[e] = pk3(s*x, s*y, s*z);
        atomicAdd(&sbin[bg + rep_slot], rep);
    }
    __syncthreads();
    if (threadIdx.x < NG) {
        float sum = 0.f;
        #pragma unroll
        for (int k = 0; k < 8; ++k) sum += sbin[threadIdx.x + k*RSTRIDE];
        bins_out[(size_t)blockIdx.x * NG + threadIdx.x] = sum;
    }
}

// K7: reduce per-block bin partials (NB x 32) -> e_graph (single block, no atomics)
__global__ __launch_bounds__(1024) void k7_bins(
        const float* __restrict__ bins, float* __restrict__ e_graph, int NB)
{
    __shared__ float sacc[1024];
    const int t = threadIdx.x;
    float a = 0.f;
    const int total = NB * NG;
    for (int i = t; i < total; i += 1024) a += bins[i];   // stride 1024 ≡ 0 mod 32
    sacc[t] = a;
    __syncthreads();
    for (int s = 512; s >= NG; s >>= 1) {
        if (t < s) sacc[t] += sacc[t + s];
        __syncthreads();
    }
    if (t < NG) e_graph[t] += sacc[t];
}

__device__ __forceinline__ void fscat64(double* sf, int base, int d, int s, double p) {
    unsigned ld = (unsigned)(d - base);
    if (ld < T_C) lds_fadd64(&sf[ld], -p);
    unsigned ls = (unsigned)(s - base);
    if (ls < T_C) lds_fadd64(&sf[ls],  p);
}

// K5: force scatter; ONE packed f64 LDS atomic per taken endpoint (pd precomputed)
__global__ __launch_bounds__(512) void k5_pk64(
        const double* __restrict__ pd, const int* __restrict__ src,
        const int* __restrict__ dst,
        double* __restrict__ scratch, int E, int NT, int NC)
{
    __shared__ double sf[T_C];
    int t, c;
    map_tc(blockIdx.x, NT, NC, &t, &c);
    const int base = t * T_C;
    for (int i = threadIdx.x; i < T_C; i += blockDim.x) sf[i] = 0.0;
    __syncthreads();
    const int NQ = E >> 2;
    const int cq = (NQ + NC - 1) / NC;
    const int q0 = c*cq;
    const int q1 = (q0 + cq < NQ) ? (q0 + cq) : NQ;
    const double2* pd2 = (const double2*)pd;
    const int4* d4 = (const int4*)dst;
    const int4* s4 = (const int4*)src;
    for (int q = q0 + (int)threadIdx.x; q < q1; q += (int)blockDim.x) {
        double2 pa = pd2[2*q], pb = pd2[2*q+1];
        int4 dd = d4[q]; int4 ss = s4[q];
        fscat64(sf, base, dd.x, ss.x, pa.x);
        fscat64(sf, base, dd.y, ss.y, pa.y);
        fscat64(sf, base, dd.z, ss.z, pb.x);
        fscat64(sf, base, dd.w, ss.w, pb.y);
    }
    if (c == NC-1) {
        for (int e = (NQ<<2) + (int)threadIdx.x; e < E; e += (int)blockDim.x) {
            fscat64(sf, base, dst[e], src[e], pd[e]);
        }
    }
    __syncthreads();
    size_t sb = (size_t)(t * NC + c) * T_C;
    for (int i = threadIdx.x; i < T_C; i += blockDim.x) scratch[sb + i] = sf[i];
}

// K6: sum packed chunks, decode fields -> forces (fully overwrites output)
__global__ __launch_bounds__(256) void k6_pk64(
        const double* __restrict__ scratch, float* __restrict__ forces,
        int N, int NC)
{
    int n = blockIdx.x*blockDim.x + threadIdx.x;
    if (n >= N) return;
    int t = n / T_C; int off = n - t*T_C;
    const double* bp = scratch + ((size_t)t*NC)*T_C + off;
    double V = 0.0;
    for (int k = 0; k < NC; ++k) V += bp[(size_t)k*T_C];
    double h1 = rint(V * (1.0/PK_K1));
    double rem = V - h1 * PK_K1;
    double h2 = rint(rem * (1.0/PK_K2));
    double Z = rem - h2 * PK_K2;
    forces[3*n+0] = (float)(h1 * (1.0/(double)PK_Q));
    forces[3*n+1] = (float)(h2 * (1.0/(double)PK_Q));
    forces[3*n+2] = (float)Z;
}

// ============== FALLBACK PATH (atomic kernels, any ws_size) ==============

__global__ __launch_bounds__(256) void fb_pass1(
        const float* __restrict__ r, const int* __restrict__ dst,
        const int* __restrict__ n2g,
        const float* __restrict__ p_da, const float* __restrict__ p_dl,
        const float* __restrict__ p_ra, const float* __restrict__ p_rl,
        float* __restrict__ local_density, float* __restrict__ e_graph, int E)
{
    __shared__ float sbin[NG];
    if (threadIdx.x < NG) sbin[threadIdx.x] = 0.f;
    __syncthreads();
    const float Ad = softplus_f(*p_da), Ld = softplus_f(*p_dl);
    const float Ar = softplus_f(*p_ra), Lr = softplus_f(*p_rl);
    const int stride = gridDim.x * blockDim.x;
    for (int e = blockIdx.x*blockDim.x + threadIdx.x; e < E; e += stride) {
        float x = r[3*e], y = r[3*e+1], z = r[3*e+2];
        float bl = sqrtf(x*x + y*y + z*z);
        int de = dst[e];
        atomicAdd(&local_density[de], Ad*expf(-Ld*bl));
        atomicAdd(&sbin[n2g[de]], Ar*expf(-Lr*bl));
    }
    __syncthreads();
    if (threadIdx.x < NG) atomicAdd(&e_graph[threadIdx.x], sbin[threadIdx.x]);
}

__global__ __launch_bounds__(256) void fb_pass2(
        float* __restrict__ ld_g, const int* __restrict__ n2g,
        const float* __restrict__ p_ea, float* __restrict__ e_graph, int N)
{
    __shared__ float sbin[NG];
    if (threadIdx.x < NG) sbin[threadIdx.x] = 0.f;
    __syncthreads();
    const float Ae = softplus_f(*p_ea);
    const int stride = gridDim.x * blockDim.x;
    for (int n = blockIdx.x*blockDim.x + threadIdx.x; n < N; n += stride) {
        float l = ld_g[n];
        float s = sqrtf(fmaxf(l, 1e-12f));
        atomicAdd(&sbin[n2g[n]], -Ae*s);
        ld_g[n] = (l >= 1e-12f) ? (-0.5f*Ae/s) : 0.f;
    }
    __syncthreads();
    if (threadIdx.x < NG) atomicAdd(&e_graph[threadIdx.x], sbin[threadIdx.x]);
}

__global__ __launch_bounds__(256) void fb_pass3(
        const float* __restrict__ r, const int* __restrict__ src,
        const int* __restrict__ dst, const float* __restrict__ g,
        const float* __restrict__ p_da, const float* __restrict__ p_dl,
        const float* __restrict__ p_ra, const float* __restrict__ p_rl,
        float* __restrict__ forces, int E)
{
    const float Ad = softplus_f(*p_da), Ld = softplus_f(*p_dl);
    const float Ar = softplus_f(*p_ra), Lr = softplus_f(*p_rl);
    const int stride = gridDim.x * blockDim.x;
    for (int e = blockIdx.x*blockDim.x + threadIdx.x; e < E; e += stride) {
        float x = r[3*e], y = r[3*e+1], z = r[3*e+2];
        float bl = sqrtf(x*x + y*y + z*z);
        int de = dst[e], se = src[e];
        float dEdb = g[de]*(-Ld*Ad*expf(-Ld*bl)) - Lr*Ar*expf(-Lr*bl);
        float s = (bl > 0.f) ? dEdb/bl : 0.f;
        float fx = s*x, fy = s*y, fz = s*z;
        atomicAdd(&forces[3*de+0], -fx); atomicAdd(&forces[3*de+1], -fy); atomicAdd(&forces[3*de+2], -fz);
        atomicAdd(&forces[3*se+0],  fx); atomicAdd(&forces[3*se+1],  fy); atomicAdd(&forces[3*se+2],  fz);
    }
}

extern "C" void kernel_launch(void* const* d_in, const int* in_sizes, int n_in,
                              void* d_out, int out_size, void* d_ws, size_t ws_size,
                              hipStream_t stream) {
    const float* r    = (const float*)d_in[0];
    const int*   src  = (const int*)d_in[1];
    const int*   dst  = (const int*)d_in[2];
    const int*   n2g  = (const int*)d_in[3];
    const float* p_da = (const float*)d_in[4];
    const float* p_dl = (const float*)d_in[5];
    const float* p_ra = (const float*)d_in[6];
    const float* p_rl = (const float*)d_in[7];
    const float* p_ea = (const float*)d_in[8];

    const int E = in_sizes[1];
    const int N = in_sizes[3];

    float* e_graph = (float*)d_out;
    float* forces  = (float*)d_out + NG;

    const int E4 = (E + 3) & ~3;
    const int NT_D = (N + T_N - 1) / T_N;   // 3
    const int NT_C = (N + T_C - 1) / T_C;   // 5

    const int NQ = E >> 2;
    int ge = (NQ + 255) / 256; if (ge > 2048) ge = 2048;

    const size_t wsf_n    = ws_size / 4;
    const size_t n_ld     = ((size_t)N + 63) & ~(size_t)63;
    const size_t off_edge = n_ld;                               // 8B-aligned (n_ld 64-aligned)
    const size_t off_bins = off_edge + (size_t)2 * (size_t)E4;  // dens f32 / pd f64 overlay
    const size_t off_scr  = off_bins + (((size_t)ge * NG + 63) & ~(size_t)63);

    long avail = (long)wsf_n - (long)off_scr;
    int NC_D = 0, NC_F = 0;
    if (avail > 0) {
        long cd = avail / ((long)NT_D * T_N);        // floats per density chunk
        long cf = avail / ((long)NT_C * T_C * 2);    // floats per packed force chunk
        NC_D = (int)(cd > 80 ? 80 : cd);
        NC_F = (int)(cf > 48 ? 48 : cf);
        if (NC_D >= 8) NC_D &= ~7;
        if (NC_F >= 8) NC_F &= ~7;
    }

    if (NC_D >= 1 && NC_F >= 1) {
        float*  ld_g     = (float*)d_ws;              // g_enc[N]
        float*  edgebuf  = (float*)d_ws + off_edge;   // dens[E4] f32, later pd[E] f64
        double* pd       = (double*)edgebuf;
        float*  bins     = (float*)d_ws + off_bins;   // ge x 32 partials
        float*  scratchf = (float*)d_ws + off_scr;
        double* scratchd = (double*)scratchf;

        hipMemsetAsync(d_out, 0, NG * sizeof(float), stream);

        k1_dens<<<ge, 256, 0, stream>>>(r, p_da, p_dl, edgebuf, E);
        k2_dens_tiles<<<NT_D * NC_D, 512, 0, stream>>>(edgebuf, dst, scratchf,
                                                       E, NT_D, NC_D);
        k3_node<<<(N + 255) / 256, 256, 0, stream>>>(scratchf, n2g, p_ea,
                                                     ld_g, e_graph, N, NC_D);
        k4_pd<<<ge, 256, 0, stream>>>(r, dst, ld_g, p_da, p_dl, p_ra, p_rl,
                                      pd, bins, E);
        k7_bins<<<1, 1024, 0, stream>>>(bins, e_graph, ge);
        k5_pk64<<<NT_C * NC_F, 512, 0, stream>>>(pd, src, dst,
                                                 scratchd, E, NT_C, NC_F);
        k6_pk64<<<(N + 255) / 256, 256, 0, stream>>>(scratchd, forces, N, NC_F);
    } else {
        float* ld_g = (float*)d_ws;
        hipMemsetAsync(d_out, 0, (size_t)out_size * sizeof(float), stream);
        hipMemsetAsync(d_ws, 0, (size_t)N * sizeof(float), stream);
        int geb = (E + 255) / 256; if (geb > 2048) geb = 2048;
        fb_pass1<<<geb, 256, 0, stream>>>(r, dst, n2g, p_da, p_dl, p_ra, p_rl,
                                          ld_g, e_graph, E);
        fb_pass2<<<(N + 255) / 256, 256, 0, stream>>>(ld_g, n2g, p_ea, e_graph, N);
        fb_pass3<<<geb, 256, 0, stream>>>(r, src, dst, ld_g, p_da, p_dl, p_ra, p_rl,
                                          forces, E);
    }
}